// Round 9
// baseline (567.356 us; speedup 1.0000x reference)
//
#include <hip/hip_runtime.h>
#include <math.h>
#include <string.h>

#define Nn 4000
#define Dd 256
#define Tt 52
#define Kk 20
#define Pp 100
#define CH 4          // t-chunks for data kernel
#define TC 13         // Tt / CH
#define GRID_D ((Nn / 8) * CH)   // 2000

// ws layout (float offsets) — every slot read later is written every launch
#define OFF_W       0        // 5408: Kinv_lam*0.5/N | Kinv_phi*0.5/D (memcpy'd)
#define OFF_MLAM_P  5408     // 125 * 2704 partial Grams (end 343408)
#define OFF_MPHI_P  343408   // 20  * 2704 partial Grams (end 397488)
#define OFF_DLP     397488   // 2000 per-block data-loss partials (end 399488)
#define OFF_CNT     399488   // completion counter (end 399489, pad to 399492)
#define OFF_EVP     399492   // u8[ng][d][8] = 256000 float slots (end 655492)
#define OFF_PHIP2   655492   // float2[t][10][d] : 266240 floats (end 921732)
#define OFF_THETA   921732   // [t][n][k] : 4160000 floats (end 5081732)

#define GR_ROWS 128

// prep role ranges
#define RB_PHIP0   0      // 52 blocks: sigmoid(phi) -> phip2[t][k/2][d][2]
#define RB_THETA0  52     // 813 blocks: softmax -> theta_t
#define RB_GPHI0   865    // 20 blocks: gram of phi deviations (2 tiles = 5120 rows)
#define RB_GLAM0   885    // 125 blocks: gram of lambda deviations (5 tiles = 80000)
#define RB_EVP0    1010   // 500 blocks: ev -> [ng][d][8] u8 pack
#define RB_TOTAL   1510

// ---------------- merged prep kernel ----------------
__global__ __launch_bounds__(256) void prep_kernel(
    const float* __restrict__ lam, const float* __restrict__ phi,
    const float* __restrict__ gamma, const float* __restrict__ G,
    const float* __restrict__ logit_prev, const int* __restrict__ ev,
    float* __restrict__ theta_t, float2* __restrict__ phip2,
    uint2* __restrict__ evp2, unsigned int* __restrict__ cnt,
    float* __restrict__ Mlam_p, float* __restrict__ Mphi_p) {
    __shared__ float rows[GR_ROWS][56];
    __shared__ float meanv[GR_ROWS];
    const int bx = blockIdx.x, tid = threadIdx.x;

    if (bx < RB_THETA0) {
        if (bx == 0 && tid == 0) *cnt = 0u;          // completion counter reset
        // phip2[t][kp][d] = {sig(phi[2kp][d][t]), sig(phi[2kp+1][d][t])}
        const int t = bx, d = tid;
        float v[Kk];
#pragma unroll
        for (int k = 0; k < Kk; ++k) {
            float x = phi[(k * Dd + d) * Tt + t];    // stride-208 gather, L2-served
            v[k] = 1.f / (1.f + __expf(-x));
        }
        float2* o = phip2 + (size_t)t * 10 * Dd + d;
#pragma unroll
        for (int kp = 0; kp < 10; ++kp)
            o[kp * Dd] = make_float2(v[2 * kp], v[2 * kp + 1]);  // coalesced
        return;
    }
    if (bx < RB_GPHI0) {
        // theta_t[t][n][k] = softmax_k(lambda[n][k][t]); thread per (n,t)
        int gid = (bx - RB_THETA0) * 256 + tid;
        if (gid >= Nn * Tt) return;
        int n = gid / Tt, t = gid - n * Tt;
        const float* base = lam + n * Kk * Tt + t;
        float v[Kk];
        float m = -1e30f;
#pragma unroll
        for (int k = 0; k < Kk; ++k) { v[k] = base[k * Tt]; m = fmaxf(m, v[k]); }
        float s = 0.f;
#pragma unroll
        for (int k = 0; k < Kk; ++k) { v[k] = __expf(v[k] - m); s += v[k]; }
        float inv = 1.f / s;
        float* o = theta_t + ((size_t)t * Nn + n) * Kk;
#pragma unroll
        for (int k = 0; k < Kk; ++k) o[k] = v[k] * inv;
        return;
    }
    if (bx < RB_GLAM0) {
        // partial Gram of (phi - logit_prev); 2 tiles; own output slot
        int slot = bx - RB_GPHI0;                    // 0..19
        int ta = tid % 13, tb = tid / 13;
        float acc[4][4] = {};
        for (int it = 0; it < 2; ++it) {
            int R0 = (slot * 2 + it) * GR_ROWS;
            __syncthreads();
            for (int idx = tid; idx < GR_ROWS * Tt; idx += 256) {
                int r = idx / Tt, t = idx - r * Tt;
                int R = R0 + r;
                rows[r][t] = phi[R * Tt + t] - logit_prev[(R & 255) * Tt + t];
            }
            __syncthreads();
            if (tb < 13) {
                for (int r = 0; r < GR_ROWS; ++r) {
                    float4 a = *(const float4*)&rows[r][4 * ta];
                    float4 b = *(const float4*)&rows[r][4 * tb];
                    float av[4] = {a.x, a.y, a.z, a.w};
                    float bv[4] = {b.x, b.y, b.z, b.w};
#pragma unroll
                    for (int i = 0; i < 4; ++i)
#pragma unroll
                        for (int j = 0; j < 4; ++j) acc[i][j] += av[i] * bv[j];
                }
            }
        }
        if (tb < 13)
#pragma unroll
            for (int i = 0; i < 4; ++i)
#pragma unroll
                for (int j = 0; j < 4; ++j)
                    Mphi_p[slot * 2704 + (4 * ta + i) * Tt + 4 * tb + j] = acc[i][j];
        return;
    }
    if (bx < RB_EVP0) {
        // partial Gram of (lambda - G@gamma); 5 tiles; own output slot
        int slot = bx - RB_GLAM0;                    // 0..124
        int ta = tid % 13, tb = tid / 13;
        float acc[4][4] = {};
        for (int it = 0; it < 5; ++it) {
            int R0 = (slot * 5 + it) * GR_ROWS;
            __syncthreads();
            if (tid < GR_ROWS) {
                int R = R0 + tid;
                int n = R / Kk, k = R - n * Kk;
                float m = 0.f;
                for (int p = 0; p < Pp; ++p) m += G[n * Pp + p] * gamma[p * Kk + k];
                meanv[tid] = m;
            }
            __syncthreads();
            for (int idx = tid; idx < GR_ROWS * Tt; idx += 256) {
                int r = idx / Tt, t = idx - r * Tt;
                int R = R0 + r;
                rows[r][t] = lam[R * Tt + t] - meanv[r];
            }
            __syncthreads();
            if (tb < 13) {
                for (int r = 0; r < GR_ROWS; ++r) {
                    float4 a = *(const float4*)&rows[r][4 * ta];
                    float4 b = *(const float4*)&rows[r][4 * tb];
                    float av[4] = {a.x, a.y, a.z, a.w};
                    float bv[4] = {b.x, b.y, b.z, b.w};
#pragma unroll
                    for (int i = 0; i < 4; ++i)
#pragma unroll
                        for (int j = 0; j < 4; ++j) acc[i][j] += av[i] * bv[j];
                }
            }
        }
        if (tb < 13)
#pragma unroll
            for (int i = 0; i < 4; ++i)
#pragma unroll
                for (int j = 0; j < 4; ++j)
                    Mlam_p[slot * 2704 + (4 * ta + i) * Tt + 4 * tb + j] = acc[i][j];
        return;
    }
    {
        // evp2[ng][d] = 8 packed u8 event times for the ng's 8 n's
        int ng = bx - RB_EVP0;                       // 0..499
        int n0 = ng * 8;
        unsigned a = 0, b = 0;
#pragma unroll
        for (int g = 0; g < 4; ++g)
            a |= ((unsigned)ev[(n0 + g) * Dd + tid] & 255u) << (8 * g);
#pragma unroll
        for (int g = 4; g < 8; ++g)
            b |= ((unsigned)ev[(n0 + g) * Dd + tid] & 255u) << (8 * (g - 4));
        evp2[(size_t)ng * Dd + tid] = make_uint2(a, b);   // coalesced 8B store
        return;
    }
}

// ---------------- data loss kernel + folded final reduction ----------------
// grid 2000: ng = blockIdx>>2 (8 n's), chunk = blockIdx&3 (13 t's), 256 d-lanes.
// theta via wave-uniform s_load; MLP as float2 -> v_pk_fma_f32; last block
// (completion counter) performs the final scalar reduction.
__global__ __launch_bounds__(256) void data_kernel(const float* __restrict__ theta_t,
                                                   const float2* __restrict__ phip2,
                                                   const float* __restrict__ Y,
                                                   const uint2* __restrict__ evp2,
                                                   float* __restrict__ ws,
                                                   float* __restrict__ out,
                                                   unsigned int* __restrict__ cnt) {
    __shared__ float wsum[4];
    __shared__ int isLast;
    const int tid = threadIdx.x;
    const int d = tid;
    const int ng = blockIdx.x >> 2;
    const int t0 = (blockIdx.x & 3) * TC;
    const int n0 = ng * 8;

    uint2 ee = evp2[(size_t)ng * Dd + d];            // ONE coalesced 8B load
    int e[8];
    e[0] = ee.x & 255; e[1] = (ee.x >> 8) & 255;
    e[2] = (ee.x >> 16) & 255; e[3] = (ee.x >> 24) & 255;
    e[4] = ee.y & 255; e[5] = (ee.y >> 8) & 255;
    e[6] = (ee.y >> 16) & 255; e[7] = (ee.y >> 24) & 255;

    float Yv[8], acc[8], pie[8], prod[8];
#pragma unroll
    for (int g = 0; g < 8; ++g) {
        acc[g] = 0.f; prod[g] = 1.f; pie[g] = 0.5f; Yv[g] = 0.f;
        if (e[g] >= t0 && e[g] < t0 + TC)            // only e-owning chunk gathers Y
            Yv[g] = __builtin_nontemporal_load(
                Y + ((size_t)((n0 + g) * Dd + d)) * Tt + e[g]);
    }

    for (int j = 0; j < TC; ++j) {
        int t = t0 + j;
        float2 pv[10];
        const float2* pt = phip2 + (size_t)t * 10 * Dd + d;
#pragma unroll
        for (int kp = 0; kp < 10; ++kp) pv[kp] = pt[kp * Dd];   // dwordx2, coalesced
#pragma unroll
        for (int g = 0; g < 8; ++g) {
            // wave-uniform address -> scalar s_load path
            const float2* th = (const float2*)(theta_t + ((size_t)t * Nn + n0 + g) * Kk);
            float2 s2 = make_float2(0.f, 0.f);
#pragma unroll
            for (int kp = 0; kp < 10; ++kp) {
                float2 a = th[kp];
                s2.x += a.x * pv[kp].x;              // packs to v_pk_fma_f32
                s2.y += a.y * pv[kp].y;
            }
            float pi = s2.x + s2.y;
            pi = fminf(fmaxf(pi, 1e-8f), 1.0f - 1e-8f);
            prod[g] *= (t <= e[g]) ? (1.f - pi) : 1.f;   // >= 1e-32 per 4-group
            pie[g] = (t == e[g]) ? pi : pie[g];
        }
        if ((j & 3) == 3 || j == TC - 1) {
#pragma unroll
            for (int g = 0; g < 8; ++g) { acc[g] += __logf(prod[g]); prod[g] = 1.f; }
        }
    }
    float tsum = 0.f;
#pragma unroll
    for (int g = 0; g < 8; ++g)
        tsum += acc[g] + Yv[g] * (__logf(pie[g]) - __logf(1.f - pie[g]));
    for (int off = 32; off; off >>= 1) tsum += __shfl_down(tsum, off, 64);
    if ((tid & 63) == 0) wsum[tid >> 6] = tsum;
    __syncthreads();
    if (tid == 0) {
        ws[OFF_DLP + blockIdx.x] = -(wsum[0] + wsum[1] + wsum[2] + wsum[3]);
        __threadfence();                             // release DLp
        unsigned prev = atomicAdd(cnt, 1u);
        isLast = (prev == GRID_D - 1) ? 1 : 0;
    }
    __syncthreads();
    if (!isLast) return;

    // ---- folded final reduction (one block, 256 threads) ----
    __threadfence();                                 // acquire others' DLp
    double s = 0.0;
    for (int i = tid; i < 2704; i += 256) {
        double ml = 0.0, mp = 0.0;
        for (int b = 0; b < 125; ++b) ml += (double)ws[OFF_MLAM_P + b * 2704 + i];
        for (int b = 0; b < 20; ++b)  mp += (double)ws[OFF_MPHI_P + b * 2704 + i];
        s += (double)ws[OFF_W + i] * ml + (double)ws[OFF_W + 2704 + i] * mp;
    }
    double dl = 0.0;
    for (int i = tid; i < GRID_D; i += 256) dl += (double)ws[OFF_DLP + i];
    s += dl / Nn;
    __shared__ double red[256];
    red[tid] = s;
    __syncthreads();
    for (int off = 128; off; off >>= 1) {
        if (tid < off) red[tid] += red[tid + off];
        __syncthreads();
    }
    if (tid == 0) out[0] = (float)red[0];
}

// ------- host-side constant math (runs ONCE at dlopen, never inside launch) -------

static void build_K_f(double ls_in, float Kf[52][52]) {
    float ls = (float)ls_in;
    float ls2 = ls * ls;
    for (int i = 0; i < 52; ++i)
        for (int j = 0; j < 52; ++j) {
            float sq = (float)((i - j) * (i - j));
            float arg = (-0.5f * sq) / ls2;
            Kf[i][j] = expf(arg);
        }
}

static void jacobi_eig(double a[52][52], double ev[52]) {
    const int n = 52;
    for (int sweep = 0; sweep < 100; ++sweep) {
        double off = 0;
        for (int p = 0; p < n - 1; ++p)
            for (int q = p + 1; q < n; ++q) off += a[p][q] * a[p][q];
        if (off < 1e-24) break;
        for (int p = 0; p < n - 1; ++p)
            for (int q = p + 1; q < n; ++q) {
                double apq = a[p][q];
                if (fabs(apq) < 1e-300) continue;
                double th = (a[q][q] - a[p][p]) / (2.0 * apq);
                double t = (th >= 0 ? 1.0 : -1.0) / (fabs(th) + sqrt(th * th + 1.0));
                double c = 1.0 / sqrt(t * t + 1.0), s = t * c;
                for (int i = 0; i < n; ++i) {
                    double aip = a[i][p], aiq = a[i][q];
                    a[i][p] = c * aip - s * aiq;
                    a[i][q] = s * aip + c * aiq;
                }
                for (int i = 0; i < n; ++i) {
                    double api = a[p][i], aqi = a[q][i];
                    a[p][i] = c * api - s * aqi;
                    a[q][i] = s * api + c * aqi;
                }
            }
    }
    for (int i = 0; i < n; ++i) ev[i] = a[i][i];
}

static void build_A(const float Kf[52][52], double jitter, double A[52][52]) {
    float jf = (float)jitter;
    for (int i = 0; i < 52; ++i)
        for (int j = 0; j < 52; ++j) A[i][j] = (double)Kf[i][j];
    for (int i = 0; i < 52; ++i) A[i][i] = (double)(float)(Kf[i][i] + jf);
}

static double cond_of(const float Kf[52][52], double jitter) {
    double A[52][52], ev[52];
    build_A(Kf, jitter, A);
    jacobi_eig(A, ev);
    double mx = 0.0, mn = 1e300;
    for (int i = 0; i < 52; ++i) {
        double a = fabs(ev[i]);
        if (a > mx) mx = a;
        if (a < mn) mn = a;
    }
    if (mn <= 0.0) return 1e300;
    return mx / mn;
}

static double find_jitter(const float Kf[52][52]) {
    double jitter = 1e-4;
    while (true) {
        if (cond_of(Kf, jitter) < 1e4) break;
        jitter *= 2.0;
        if (jitter > 0.1) break;
    }
    return jitter;
}

static void chol_inv_scaled(const float Kf[52][52], double jitter, double scale,
                            float* out) {
    const int n = 52;
    double A[52][52], L[52][52];
    build_A(Kf, jitter, A);
    memset(L, 0, sizeof(L));
    for (int j = 0; j < n; ++j) {
        double s = A[j][j];
        for (int k = 0; k < j; ++k) s -= L[j][k] * L[j][k];
        L[j][j] = sqrt(s);
        for (int i = j + 1; i < n; ++i) {
            double v = A[i][j];
            for (int k = 0; k < j; ++k) v -= L[i][k] * L[j][k];
            L[i][j] = v / L[j][j];
        }
    }
    for (int c = 0; c < n; ++c) {
        double y[52], x[52];
        for (int i = 0; i < n; ++i) {
            double v = (i == c) ? 1.0 : 0.0;
            for (int k = 0; k < i; ++k) v -= L[i][k] * y[k];
            y[i] = v / L[i][i];
        }
        for (int i = n - 1; i >= 0; --i) {
            double v = y[i];
            for (int k = i + 1; k < n; ++k) v -= L[k][i] * x[k];
            x[i] = v / L[i][i];
        }
        for (int i = 0; i < n; ++i) out[i * 52 + c] = (float)(x[i] * scale);
    }
}

struct KinvInit {
    float* w;   // PINNED: [0:2704) Kinv_lam*0.5/N, [2704:5408) Kinv_phi*0.5/D
    KinvInit() {
        if (hipHostMalloc((void**)&w, 5408 * sizeof(float)) != hipSuccess)
            w = (float*)malloc(5408 * sizeof(float));
        float Kf[52][52];
        build_K_f(52.0 / 4.0, Kf);
        chol_inv_scaled(Kf, find_jitter(Kf), 0.5 / Nn, w);
        build_K_f(52.0 / 3.0, Kf);
        chol_inv_scaled(Kf, find_jitter(Kf), 0.5 / Dd, w + 2704);
    }
};
static KinvInit g_kinv;   // dlopen-time; kernel_launch identical every call

// ---------------- launch: memcpy + 2 kernels ----------------

extern "C" void kernel_launch(void* const* d_in, const int* in_sizes, int n_in,
                              void* d_out, int out_size, void* d_ws, size_t ws_size,
                              hipStream_t stream) {
    (void)in_sizes; (void)n_in; (void)out_size; (void)ws_size;
    const float* lam        = (const float*)d_in[0];
    const float* phi        = (const float*)d_in[1];
    const float* gamma      = (const float*)d_in[2];
    const float* G          = (const float*)d_in[3];
    const float* Y          = (const float*)d_in[4];
    const float* logit_prev = (const float*)d_in[5];
    const int*   ev         = (const int*)d_in[6];
    float* out = (float*)d_out;
    float* ws  = (float*)d_ws;

    hipMemcpyAsync(ws + OFF_W, g_kinv.w, 5408 * sizeof(float),
                   hipMemcpyHostToDevice, stream);

    prep_kernel<<<RB_TOTAL, 256, 0, stream>>>(
        lam, phi, gamma, G, logit_prev, ev,
        ws + OFF_THETA, (float2*)(ws + OFF_PHIP2),
        (uint2*)(ws + OFF_EVP), (unsigned int*)(ws + OFF_CNT),
        ws + OFF_MLAM_P, ws + OFF_MPHI_P);
    data_kernel<<<GRID_D, 256, 0, stream>>>(
        ws + OFF_THETA, (const float2*)(ws + OFF_PHIP2), Y,
        (const uint2*)(ws + OFF_EVP), ws, out, (unsigned int*)(ws + OFF_CNT));
}

// Round 10
// 442.779 us; speedup vs baseline: 1.2814x; 1.2814x over previous
//
#include <hip/hip_runtime.h>
#include <math.h>
#include <string.h>

#define Nn 4000
#define Dd 256
#define Tt 52
#define Kk 20
#define Pp 100
#define CH 4          // t-chunks for data kernel
#define TC 13         // Tt / CH
#define GRID_D ((Nn / 8) * CH)   // 2000

// ws layout (float offsets) — every slot read later is written every launch
#define OFF_W       0        // 5408: Kinv_lam*0.5/N | Kinv_phi*0.5/D (memcpy'd)
#define OFF_MLAM_P  5408     // 125 * 2704 partial Grams (end 343408)
#define OFF_MPHI_P  343408   // 20  * 2704 partial Grams (end 397488)
#define OFF_DLP     397488   // 2000 per-block data-loss partials (end 399488)
#define OFF_EVP     399488   // uint2[ng][d]: bytes = e | (Y<<7); 256000 floats
#define OFF_PHIP    655488   // [t][k][d] : 266240 floats (end 921728)
#define OFF_THETA   921728   // [t][n][k] : 4160000 floats (end 5081728)

#define GR_ROWS 128

// prep role ranges
#define RB_PHIP0   0      // 52 blocks: sigmoid(phi) transpose
#define RB_THETA0  52     // 813 blocks: softmax -> theta_t
#define RB_GPHI0   865    // 20 blocks: gram of phi deviations (2 tiles = 5120 rows)
#define RB_GLAM0   885    // 125 blocks: gram of lambda deviations (5 tiles = 80000)
#define RB_EVY0    1010   // 1000 blocks: ev + Y-at-event -> packed bytes
#define RB_TOTAL   2010

// ---------------- merged prep kernel ----------------
__global__ __launch_bounds__(256) void prep_kernel(
    const float* __restrict__ lam, const float* __restrict__ phi,
    const float* __restrict__ gamma, const float* __restrict__ G,
    const float* __restrict__ logit_prev, const int* __restrict__ ev,
    const float* __restrict__ Y,
    float* __restrict__ theta_t, float* __restrict__ phip_t,
    unsigned int* __restrict__ evy,
    float* __restrict__ Mlam_p, float* __restrict__ Mphi_p) {
    __shared__ float rows[GR_ROWS][56];
    __shared__ float meanv[GR_ROWS];
    const int bx = blockIdx.x, tid = threadIdx.x;

    if (bx < RB_THETA0) {
        // phip_t[t][k][d] = sigmoid(phi[k][d][t]); thread per (d,t)
        int gid = bx * 256 + tid;                    // d*52 + t
        int d = gid / Tt, t = gid - d * Tt;
        float v[Kk];
#pragma unroll
        for (int k = 0; k < Kk; ++k) {
            float x = phi[k * (Dd * Tt) + gid];      // coalesced in t
            v[k] = 1.f / (1.f + __expf(-x));
        }
#pragma unroll
        for (int k = 0; k < Kk; ++k)
            phip_t[((size_t)t * Kk + k) * Dd + d] = v[k];
        return;
    }
    if (bx < RB_GPHI0) {
        // theta_t[t][n][k] = softmax_k(lambda[n][k][t]); thread per (n,t)
        int gid = (bx - RB_THETA0) * 256 + tid;
        if (gid >= Nn * Tt) return;
        int n = gid / Tt, t = gid - n * Tt;
        const float* base = lam + n * Kk * Tt + t;
        float v[Kk];
        float m = -1e30f;
#pragma unroll
        for (int k = 0; k < Kk; ++k) { v[k] = base[k * Tt]; m = fmaxf(m, v[k]); }
        float s = 0.f;
#pragma unroll
        for (int k = 0; k < Kk; ++k) { v[k] = __expf(v[k] - m); s += v[k]; }
        float inv = 1.f / s;
        float* o = theta_t + ((size_t)t * Nn + n) * Kk;
#pragma unroll
        for (int k = 0; k < Kk; ++k) o[k] = v[k] * inv;
        return;
    }
    if (bx < RB_GLAM0) {
        // partial Gram of (phi - logit_prev); 2 tiles; own output slot
        int slot = bx - RB_GPHI0;                    // 0..19
        int ta = tid % 13, tb = tid / 13;
        float acc[4][4] = {};
        for (int it = 0; it < 2; ++it) {
            int R0 = (slot * 2 + it) * GR_ROWS;
            __syncthreads();
            for (int idx = tid; idx < GR_ROWS * Tt; idx += 256) {
                int r = idx / Tt, t = idx - r * Tt;
                int R = R0 + r;
                rows[r][t] = phi[R * Tt + t] - logit_prev[(R & 255) * Tt + t];
            }
            __syncthreads();
            if (tb < 13) {
                for (int r = 0; r < GR_ROWS; ++r) {
                    float4 a = *(const float4*)&rows[r][4 * ta];
                    float4 b = *(const float4*)&rows[r][4 * tb];
                    float av[4] = {a.x, a.y, a.z, a.w};
                    float bv[4] = {b.x, b.y, b.z, b.w};
#pragma unroll
                    for (int i = 0; i < 4; ++i)
#pragma unroll
                        for (int j = 0; j < 4; ++j) acc[i][j] += av[i] * bv[j];
                }
            }
        }
        if (tb < 13)
#pragma unroll
            for (int i = 0; i < 4; ++i)
#pragma unroll
                for (int j = 0; j < 4; ++j)
                    Mphi_p[slot * 2704 + (4 * ta + i) * Tt + 4 * tb + j] = acc[i][j];
        return;
    }
    if (bx < RB_EVY0) {
        // partial Gram of (lambda - G@gamma); 5 tiles; own output slot
        int slot = bx - RB_GLAM0;                    // 0..124
        int ta = tid % 13, tb = tid / 13;
        float acc[4][4] = {};
        for (int it = 0; it < 5; ++it) {
            int R0 = (slot * 5 + it) * GR_ROWS;
            __syncthreads();
            if (tid < GR_ROWS) {
                int R = R0 + tid;
                int n = R / Kk, k = R - n * Kk;
                float m = 0.f;
                for (int p = 0; p < Pp; ++p) m += G[n * Pp + p] * gamma[p * Kk + k];
                meanv[tid] = m;
            }
            __syncthreads();
            for (int idx = tid; idx < GR_ROWS * Tt; idx += 256) {
                int r = idx / Tt, t = idx - r * Tt;
                int R = R0 + r;
                rows[r][t] = lam[R * Tt + t] - meanv[r];
            }
            __syncthreads();
            if (tb < 13) {
                for (int r = 0; r < GR_ROWS; ++r) {
                    float4 a = *(const float4*)&rows[r][4 * ta];
                    float4 b = *(const float4*)&rows[r][4 * tb];
                    float av[4] = {a.x, a.y, a.z, a.w};
                    float bv[4] = {b.x, b.y, b.z, b.w};
#pragma unroll
                    for (int i = 0; i < 4; ++i)
#pragma unroll
                        for (int j = 0; j < 4; ++j) acc[i][j] += av[i] * bv[j];
                }
            }
        }
        if (tb < 13)
#pragma unroll
            for (int i = 0; i < 4; ++i)
#pragma unroll
                for (int j = 0; j < 4; ++j)
                    Mlam_p[slot * 2704 + (4 * ta + i) * Tt + 4 * tb + j] = acc[i][j];
        return;
    }
    {
        // evy: block per (ng, half); thread d packs 4 n's: byte = e | (Y@e)<<7.
        // This role owns the 65-MB random-line Y gather (1000 dedicated blocks
        // = max outstanding misses, overlapped with the dense roles above).
        int idx = bx - RB_EVY0;                      // 0..999
        int ng = idx >> 1, half = idx & 1;
        int n0 = ng * 8 + half * 4;
        unsigned a = 0;
#pragma unroll
        for (int g = 0; g < 4; ++g) {
            int nd = (n0 + g) * Dd + tid;
            unsigned e = (unsigned)ev[nd] & 63u;     // coalesced
            float y = __builtin_nontemporal_load(Y + (size_t)nd * Tt + e);
            a |= (e | (y > 0.5f ? 128u : 0u)) << (8 * g);
        }
        evy[((size_t)ng * Dd + tid) * 2 + half] = a;
        return;
    }
}

// ---------------- data loss kernel (R8-proven form) ----------------
// grid 2000: ng = blockIdx>>2 (8 n's), chunk = blockIdx&3 (13 t's), 256 d-lanes.
// theta via wave-uniform float4 s_load; log-of-product-of-4; NO Y access.
__global__ __launch_bounds__(256) void data_kernel(const float* __restrict__ theta_t,
                                                   const float* __restrict__ phip_t,
                                                   const uint2* __restrict__ evy,
                                                   float* __restrict__ DLp) {
    __shared__ float wsum[4];
    const int tid = threadIdx.x;
    const int d = tid;
    const int ng = blockIdx.x >> 2;
    const int t0 = (blockIdx.x & 3) * TC;
    const int n0 = ng * 8;

    uint2 ee = evy[(size_t)ng * Dd + d];             // ONE coalesced 8B load
    int e[8];
    float Yv[8], acc[8], pie[8], prod[8];
#pragma unroll
    for (int g = 0; g < 8; ++g) {
        unsigned byte = ((g < 4 ? ee.x : ee.y) >> (8 * (g & 3))) & 255u;
        e[g] = (int)(byte & 63u);
        Yv[g] = (byte & 128u) ? 1.f : 0.f;
        acc[g] = 0.f; prod[g] = 1.f; pie[g] = 0.5f;
    }

    for (int j = 0; j < TC; ++j) {
        int t = t0 + j;
        float pv[Kk];
        const float* pt = phip_t + (size_t)t * (Kk * Dd) + d;
#pragma unroll
        for (int k = 0; k < Kk; ++k) pv[k] = pt[k * Dd];   // coalesced, L2-hot
#pragma unroll
        for (int g = 0; g < 8; ++g) {
            // wave-uniform address -> scalar s_load_dwordx4 path (R8-proven)
            const float4* th = (const float4*)(theta_t + ((size_t)t * Nn + n0 + g) * Kk);
            float4 a0 = th[0], a1 = th[1], a2 = th[2], a3 = th[3], a4 = th[4];
            float pi = a0.x * pv[0] + a0.y * pv[1] + a0.z * pv[2] + a0.w * pv[3]
                     + a1.x * pv[4] + a1.y * pv[5] + a1.z * pv[6] + a1.w * pv[7]
                     + a2.x * pv[8] + a2.y * pv[9] + a2.z * pv[10] + a2.w * pv[11]
                     + a3.x * pv[12] + a3.y * pv[13] + a3.z * pv[14] + a3.w * pv[15]
                     + a4.x * pv[16] + a4.y * pv[17] + a4.z * pv[18] + a4.w * pv[19];
            pi = fminf(fmaxf(pi, 1e-8f), 1.0f - 1e-8f);
            prod[g] *= (t <= e[g]) ? (1.f - pi) : 1.f;     // >= 1e-32 per 4-group
            pie[g] = (t == e[g]) ? pi : pie[g];
        }
        if ((j & 3) == 3 || j == TC - 1) {
#pragma unroll
            for (int g = 0; g < 8; ++g) { acc[g] += __logf(prod[g]); prod[g] = 1.f; }
        }
    }
    float tsum = 0.f;
#pragma unroll
    for (int g = 0; g < 8; ++g)
        tsum += acc[g] + Yv[g] * (__logf(pie[g]) - __logf(1.f - pie[g]));
    for (int off = 32; off; off >>= 1) tsum += __shfl_down(tsum, off, 64);
    if ((tid & 63) == 0) wsum[tid >> 6] = tsum;
    __syncthreads();
    if (tid == 0)
        DLp[blockIdx.x] = -(wsum[0] + wsum[1] + wsum[2] + wsum[3]);
}

// out = sum(DLp)/N + <W_lam, sum Mlam_p> + <W_phi, sum Mphi_p>  (W pre-scaled)
__global__ __launch_bounds__(1024) void final_kernel(const float* __restrict__ ws,
                                                     float* __restrict__ out) {
    const int tid = threadIdx.x;
    double s = 0.0;
    for (int i = tid; i < 2704; i += 1024) {
        double ml = 0.0, mp = 0.0;
        for (int b = 0; b < 125; ++b) ml += (double)ws[OFF_MLAM_P + b * 2704 + i];
        for (int b = 0; b < 20; ++b)  mp += (double)ws[OFF_MPHI_P + b * 2704 + i];
        s += (double)ws[OFF_W + i] * ml + (double)ws[OFF_W + 2704 + i] * mp;
    }
    double dl = 0.0;
    for (int i = tid; i < GRID_D; i += 1024) dl += (double)ws[OFF_DLP + i];
    s += dl / Nn;
    __shared__ double red[1024];
    red[tid] = s;
    __syncthreads();
    for (int off = 512; off; off >>= 1) {
        if (tid < off) red[tid] += red[tid + off];
        __syncthreads();
    }
    if (tid == 0) out[0] = (float)red[0];
}

// ------- host-side constant math (runs ONCE at dlopen, never inside launch) -------

static void build_K_f(double ls_in, float Kf[52][52]) {
    float ls = (float)ls_in;
    float ls2 = ls * ls;
    for (int i = 0; i < 52; ++i)
        for (int j = 0; j < 52; ++j) {
            float sq = (float)((i - j) * (i - j));
            float arg = (-0.5f * sq) / ls2;
            Kf[i][j] = expf(arg);
        }
}

static void jacobi_eig(double a[52][52], double ev[52]) {
    const int n = 52;
    for (int sweep = 0; sweep < 100; ++sweep) {
        double off = 0;
        for (int p = 0; p < n - 1; ++p)
            for (int q = p + 1; q < n; ++q) off += a[p][q] * a[p][q];
        if (off < 1e-24) break;
        for (int p = 0; p < n - 1; ++p)
            for (int q = p + 1; q < n; ++q) {
                double apq = a[p][q];
                if (fabs(apq) < 1e-300) continue;
                double th = (a[q][q] - a[p][p]) / (2.0 * apq);
                double t = (th >= 0 ? 1.0 : -1.0) / (fabs(th) + sqrt(th * th + 1.0));
                double c = 1.0 / sqrt(t * t + 1.0), s = t * c;
                for (int i = 0; i < n; ++i) {
                    double aip = a[i][p], aiq = a[i][q];
                    a[i][p] = c * aip - s * aiq;
                    a[i][q] = s * aip + c * aiq;
                }
                for (int i = 0; i < n; ++i) {
                    double api = a[p][i], aqi = a[q][i];
                    a[p][i] = c * api - s * aqi;
                    a[q][i] = s * api + c * aqi;
                }
            }
    }
    for (int i = 0; i < n; ++i) ev[i] = a[i][i];
}

static void build_A(const float Kf[52][52], double jitter, double A[52][52]) {
    float jf = (float)jitter;
    for (int i = 0; i < 52; ++i)
        for (int j = 0; j < 52; ++j) A[i][j] = (double)Kf[i][j];
    for (int i = 0; i < 52; ++i) A[i][i] = (double)(float)(Kf[i][i] + jf);
}

static double cond_of(const float Kf[52][52], double jitter) {
    double A[52][52], ev[52];
    build_A(Kf, jitter, A);
    jacobi_eig(A, ev);
    double mx = 0.0, mn = 1e300;
    for (int i = 0; i < 52; ++i) {
        double a = fabs(ev[i]);
        if (a > mx) mx = a;
        if (a < mn) mn = a;
    }
    if (mn <= 0.0) return 1e300;
    return mx / mn;
}

static double find_jitter(const float Kf[52][52]) {
    double jitter = 1e-4;
    while (true) {
        if (cond_of(Kf, jitter) < 1e4) break;
        jitter *= 2.0;
        if (jitter > 0.1) break;
    }
    return jitter;
}

static void chol_inv_scaled(const float Kf[52][52], double jitter, double scale,
                            float* out) {
    const int n = 52;
    double A[52][52], L[52][52];
    build_A(Kf, jitter, A);
    memset(L, 0, sizeof(L));
    for (int j = 0; j < n; ++j) {
        double s = A[j][j];
        for (int k = 0; k < j; ++k) s -= L[j][k] * L[j][k];
        L[j][j] = sqrt(s);
        for (int i = j + 1; i < n; ++i) {
            double v = A[i][j];
            for (int k = 0; k < j; ++k) v -= L[i][k] * L[j][k];
            L[i][j] = v / L[j][j];
        }
    }
    for (int c = 0; c < n; ++c) {
        double y[52], x[52];
        for (int i = 0; i < n; ++i) {
            double v = (i == c) ? 1.0 : 0.0;
            for (int k = 0; k < i; ++k) v -= L[i][k] * y[k];
            y[i] = v / L[i][i];
        }
        for (int i = n - 1; i >= 0; --i) {
            double v = y[i];
            for (int k = i + 1; k < n; ++k) v -= L[k][i] * x[k];
            x[i] = v / L[i][i];
        }
        for (int i = 0; i < n; ++i) out[i * 52 + c] = (float)(x[i] * scale);
    }
}

struct KinvInit {
    float* w;   // PINNED: [0:2704) Kinv_lam*0.5/N, [2704:5408) Kinv_phi*0.5/D
    KinvInit() {
        if (hipHostMalloc((void**)&w, 5408 * sizeof(float)) != hipSuccess)
            w = (float*)malloc(5408 * sizeof(float));
        float Kf[52][52];
        build_K_f(52.0 / 4.0, Kf);
        chol_inv_scaled(Kf, find_jitter(Kf), 0.5 / Nn, w);
        build_K_f(52.0 / 3.0, Kf);
        chol_inv_scaled(Kf, find_jitter(Kf), 0.5 / Dd, w + 2704);
    }
};
static KinvInit g_kinv;   // dlopen-time; kernel_launch identical every call

// ---------------- launch: memcpy + 3 kernels ----------------

extern "C" void kernel_launch(void* const* d_in, const int* in_sizes, int n_in,
                              void* d_out, int out_size, void* d_ws, size_t ws_size,
                              hipStream_t stream) {
    (void)in_sizes; (void)n_in; (void)out_size; (void)ws_size;
    const float* lam        = (const float*)d_in[0];
    const float* phi        = (const float*)d_in[1];
    const float* gamma      = (const float*)d_in[2];
    const float* G          = (const float*)d_in[3];
    const float* Y          = (const float*)d_in[4];
    const float* logit_prev = (const float*)d_in[5];
    const int*   ev         = (const int*)d_in[6];
    float* out = (float*)d_out;
    float* ws  = (float*)d_ws;

    hipMemcpyAsync(ws + OFF_W, g_kinv.w, 5408 * sizeof(float),
                   hipMemcpyHostToDevice, stream);

    prep_kernel<<<RB_TOTAL, 256, 0, stream>>>(
        lam, phi, gamma, G, logit_prev, ev, Y,
        ws + OFF_THETA, ws + OFF_PHIP, (unsigned int*)(ws + OFF_EVP),
        ws + OFF_MLAM_P, ws + OFF_MPHI_P);
    data_kernel<<<GRID_D, 256, 0, stream>>>(
        ws + OFF_THETA, ws + OFF_PHIP, (const uint2*)(ws + OFF_EVP),
        ws + OFF_DLP);
    final_kernel<<<1, 1024, 0, stream>>>(ws, out);
}

// Round 11
// 434.975 us; speedup vs baseline: 1.3043x; 1.0179x over previous
//
#include <hip/hip_runtime.h>
#include <math.h>
#include <string.h>

#define Nn 4000
#define Dd 256
#define Tt 52
#define Kk 20
#define Pp 100
#define CH 4          // t-chunks for data kernel
#define TC 13         // Tt / CH
#define GRID_D ((Nn / 8) * CH)   // 2000

// ws layout (float offsets) — every slot read later is written every launch
#define OFF_W       0        // 5408: Kinv_lam*0.5/N | Kinv_phi*0.5/D (memcpy'd)
#define OFF_GPART   5408     // 145 per-gram-block scalars <W, M_block> (end 5553)
#define OFF_DLP     5556     // 2000 per-block data-loss partials (end 7556)
#define OFF_CNT     7556     // completion counter (pad to 7560)
#define OFF_EVP     7560     // uint2[ng][d]: bytes = e | (Y<<7); 256000 floats
#define OFF_PHIP    263560   // [t][k][d] : 266240 floats (end 529800)
#define OFF_THETA   529800   // [t][n][k] : 4160000 floats (end 4689800)

#define GR_ROWS 128

// prep role ranges
#define RB_PHIP0   0      // 52 blocks: sigmoid(phi) transpose
#define RB_THETA0  52     // 813 blocks: softmax -> theta_t
#define RB_GPHI0   865    // 20 blocks: gram(phi dev) . W_phi -> gpart[125+slot]
#define RB_GLAM0   885    // 125 blocks: gram(lam dev) . W_lam -> gpart[slot]
#define RB_EVY0    1010   // 1000 blocks: ev + Y-at-event -> packed bytes
#define RB_TOTAL   2010

// ---------------- merged prep kernel ----------------
__global__ __launch_bounds__(256) void prep_kernel(
    const float* __restrict__ lam, const float* __restrict__ phi,
    const float* __restrict__ gamma, const float* __restrict__ G,
    const float* __restrict__ logit_prev, const int* __restrict__ ev,
    const float* __restrict__ Y,
    float* __restrict__ theta_t, float* __restrict__ phip_t,
    unsigned int* __restrict__ evy,
    const float* __restrict__ W, float* __restrict__ gpart,
    unsigned int* __restrict__ cnt) {
    __shared__ float rows[GR_ROWS][56];
    __shared__ float meanv[GR_ROWS];
    __shared__ double redd[256];
    const int bx = blockIdx.x, tid = threadIdx.x;

    if (bx < RB_THETA0) {
        if (bx == 0 && tid == 0) *cnt = 0u;          // completion counter reset
        // phip_t[t][k][d] = sigmoid(phi[k][d][t]); thread per (d,t)
        int gid = bx * 256 + tid;                    // d*52 + t
        int d = gid / Tt, t = gid - d * Tt;
        float v[Kk];
#pragma unroll
        for (int k = 0; k < Kk; ++k) {
            float x = phi[k * (Dd * Tt) + gid];      // coalesced in t
            v[k] = 1.f / (1.f + __expf(-x));
        }
#pragma unroll
        for (int k = 0; k < Kk; ++k)
            phip_t[((size_t)t * Kk + k) * Dd + d] = v[k];
        return;
    }
    if (bx < RB_GPHI0) {
        // theta_t[t][n][k] = softmax_k(lambda[n][k][t]); thread per (n,t)
        int gid = (bx - RB_THETA0) * 256 + tid;
        if (gid >= Nn * Tt) return;
        int n = gid / Tt, t = gid - n * Tt;
        const float* base = lam + n * Kk * Tt + t;
        float v[Kk];
        float m = -1e30f;
#pragma unroll
        for (int k = 0; k < Kk; ++k) { v[k] = base[k * Tt]; m = fmaxf(m, v[k]); }
        float s = 0.f;
#pragma unroll
        for (int k = 0; k < Kk; ++k) { v[k] = __expf(v[k] - m); s += v[k]; }
        float inv = 1.f / s;
        float* o = theta_t + ((size_t)t * Nn + n) * Kk;
#pragma unroll
        for (int k = 0; k < Kk; ++k) o[k] = v[k] * inv;
        return;
    }
    if (bx < RB_GLAM0) {
        // <W_phi, Gram of (phi - logit_prev) over 2 tiles> -> gpart[125+slot]
        int slot = bx - RB_GPHI0;                    // 0..19
        int ta = tid % 13, tb = tid / 13;
        float acc[4][4] = {};
        for (int it = 0; it < 2; ++it) {
            int R0 = (slot * 2 + it) * GR_ROWS;
            __syncthreads();
            for (int idx = tid; idx < GR_ROWS * Tt; idx += 256) {
                int r = idx / Tt, t = idx - r * Tt;
                int R = R0 + r;
                rows[r][t] = phi[R * Tt + t] - logit_prev[(R & 255) * Tt + t];
            }
            __syncthreads();
            if (tb < 13) {
                for (int r = 0; r < GR_ROWS; ++r) {
                    float4 a = *(const float4*)&rows[r][4 * ta];
                    float4 b = *(const float4*)&rows[r][4 * tb];
                    float av[4] = {a.x, a.y, a.z, a.w};
                    float bv[4] = {b.x, b.y, b.z, b.w};
#pragma unroll
                    for (int i = 0; i < 4; ++i)
#pragma unroll
                        for (int j = 0; j < 4; ++j) acc[i][j] += av[i] * bv[j];
                }
            }
        }
        double s = 0.0;
        if (tb < 13)
#pragma unroll
            for (int i = 0; i < 4; ++i)
#pragma unroll
                for (int j = 0; j < 4; ++j)
                    s += (double)acc[i][j] *
                         (double)W[2704 + (4 * ta + i) * Tt + 4 * tb + j];
        redd[tid] = s;
        __syncthreads();
        for (int off = 128; off; off >>= 1) {
            if (tid < off) redd[tid] += redd[tid + off];
            __syncthreads();
        }
        if (tid == 0) gpart[125 + slot] = (float)redd[0];
        return;
    }
    if (bx < RB_EVY0) {
        // <W_lam, Gram of (lambda - G@gamma) over 5 tiles> -> gpart[slot]
        int slot = bx - RB_GLAM0;                    // 0..124
        int ta = tid % 13, tb = tid / 13;
        float acc[4][4] = {};
        for (int it = 0; it < 5; ++it) {
            int R0 = (slot * 5 + it) * GR_ROWS;
            __syncthreads();
            if (tid < GR_ROWS) {
                int R = R0 + tid;
                int n = R / Kk, k = R - n * Kk;
                float m = 0.f;
                for (int p = 0; p < Pp; ++p) m += G[n * Pp + p] * gamma[p * Kk + k];
                meanv[tid] = m;
            }
            __syncthreads();
            for (int idx = tid; idx < GR_ROWS * Tt; idx += 256) {
                int r = idx / Tt, t = idx - r * Tt;
                int R = R0 + r;
                rows[r][t] = lam[R * Tt + t] - meanv[r];
            }
            __syncthreads();
            if (tb < 13) {
                for (int r = 0; r < GR_ROWS; ++r) {
                    float4 a = *(const float4*)&rows[r][4 * ta];
                    float4 b = *(const float4*)&rows[r][4 * tb];
                    float av[4] = {a.x, a.y, a.z, a.w};
                    float bv[4] = {b.x, b.y, b.z, b.w};
#pragma unroll
                    for (int i = 0; i < 4; ++i)
#pragma unroll
                        for (int j = 0; j < 4; ++j) acc[i][j] += av[i] * bv[j];
                }
            }
        }
        double s = 0.0;
        if (tb < 13)
#pragma unroll
            for (int i = 0; i < 4; ++i)
#pragma unroll
                for (int j = 0; j < 4; ++j)
                    s += (double)acc[i][j] *
                         (double)W[(4 * ta + i) * Tt + 4 * tb + j];
        redd[tid] = s;
        __syncthreads();
        for (int off = 128; off; off >>= 1) {
            if (tid < off) redd[tid] += redd[tid + off];
            __syncthreads();
        }
        if (tid == 0) gpart[slot] = (float)redd[0];
        return;
    }
    {
        // evy: block per (ng, half); thread d packs 4 n's: byte = e | (Y@e)<<7.
        // Owns the 65-MB random-line Y gather (1000 dedicated blocks).
        int idx = bx - RB_EVY0;                      // 0..999
        int ng = idx >> 1, half = idx & 1;
        int n0 = ng * 8 + half * 4;
        unsigned a = 0;
#pragma unroll
        for (int g = 0; g < 4; ++g) {
            int nd = (n0 + g) * Dd + tid;
            unsigned e = (unsigned)ev[nd] & 63u;     // coalesced
            float y = __builtin_nontemporal_load(Y + (size_t)nd * Tt + e);
            a |= (e | (y > 0.5f ? 128u : 0u)) << (8 * g);
        }
        evy[((size_t)ng * Dd + tid) * 2 + half] = a;
        return;
    }
}

// ---------------- data loss kernel + folded final ----------------
// grid 2000: ng = blockIdx>>2 (8 n's), chunk = blockIdx&3 (13 t's), 256 d-lanes.
// theta staged to LDS once (coalesced 8.3 KB), read via same-address
// ds_read_b128 broadcast (conflict-free) — replaces 520 s_load chains.
__global__ __launch_bounds__(256) void data_kernel(const float* __restrict__ theta_t,
                                                   const float* __restrict__ phip_t,
                                                   const uint2* __restrict__ evy,
                                                   float* __restrict__ ws,
                                                   float* __restrict__ out,
                                                   unsigned int* __restrict__ cnt) {
    __shared__ __align__(16) float thS[TC][8][Kk];   // 8.32 KB
    __shared__ float wsum[4];
    __shared__ double redd[256];
    __shared__ int isLast;
    const int tid = threadIdx.x;
    const int d = tid;
    const int ng = blockIdx.x >> 2;
    const int t0 = (blockIdx.x & 3) * TC;
    const int n0 = ng * 8;

    // stage theta tile: per t, 160 contiguous floats (perfectly coalesced)
    for (int idx = tid; idx < TC * 160; idx += 256) {
        int j = idx / 160, r = idx - j * 160;
        thS[j][r / Kk][r - (r / Kk) * Kk] =
            theta_t[((size_t)(t0 + j) * Nn + n0) * Kk + r];
    }

    uint2 ee = evy[(size_t)ng * Dd + d];             // ONE coalesced 8B load
    int e[8];
    float Yv[8], acc[8], pie[8], prod[8];
#pragma unroll
    for (int g = 0; g < 8; ++g) {
        unsigned byte = ((g < 4 ? ee.x : ee.y) >> (8 * (g & 3))) & 255u;
        e[g] = (int)(byte & 63u);
        Yv[g] = (byte & 128u) ? 1.f : 0.f;           // pie stays 0.5 in
        acc[g] = 0.f; prod[g] = 1.f; pie[g] = 0.5f;  // non-owning chunks -> term 0
    }
    __syncthreads();

    for (int j = 0; j < TC; ++j) {
        int t = t0 + j;
        float pv[Kk];
        const float* pt = phip_t + (size_t)t * (Kk * Dd) + d;
#pragma unroll
        for (int k = 0; k < Kk; ++k) pv[k] = pt[k * Dd];   // coalesced, L2-hot
#pragma unroll
        for (int g = 0; g < 8; ++g) {
            const float4* th = (const float4*)&thS[j][g][0];  // LDS broadcast
            float4 a0 = th[0], a1 = th[1], a2 = th[2], a3 = th[3], a4 = th[4];
            float pi = a0.x * pv[0] + a0.y * pv[1] + a0.z * pv[2] + a0.w * pv[3]
                     + a1.x * pv[4] + a1.y * pv[5] + a1.z * pv[6] + a1.w * pv[7]
                     + a2.x * pv[8] + a2.y * pv[9] + a2.z * pv[10] + a2.w * pv[11]
                     + a3.x * pv[12] + a3.y * pv[13] + a3.z * pv[14] + a3.w * pv[15]
                     + a4.x * pv[16] + a4.y * pv[17] + a4.z * pv[18] + a4.w * pv[19];
            pi = fminf(fmaxf(pi, 1e-8f), 1.0f - 1e-8f);
            prod[g] *= (t <= e[g]) ? (1.f - pi) : 1.f;     // >= 1e-32 per 4-group
            pie[g] = (t == e[g]) ? pi : pie[g];
        }
        if ((j & 3) == 3 || j == TC - 1) {
#pragma unroll
            for (int g = 0; g < 8; ++g) { acc[g] += __logf(prod[g]); prod[g] = 1.f; }
        }
    }
    float tsum = 0.f;
#pragma unroll
    for (int g = 0; g < 8; ++g)
        tsum += acc[g] + Yv[g] * (__logf(pie[g]) - __logf(1.f - pie[g]));
    for (int off = 32; off; off >>= 1) tsum += __shfl_down(tsum, off, 64);
    if ((tid & 63) == 0) wsum[tid >> 6] = tsum;
    __syncthreads();
    if (tid == 0) {
        ws[OFF_DLP + blockIdx.x] = -(wsum[0] + wsum[1] + wsum[2] + wsum[3]);
        __threadfence();                             // release DLp
        unsigned prev = atomicAdd(cnt, 1u);
        isLast = (prev == GRID_D - 1) ? 1 : 0;
    }
    __syncthreads();
    if (!isLast) return;

    // ---- folded final: 145 gram scalars + 2000 DLp (8.6 KB total) ----
    __threadfence();                                 // acquire others' DLp
    double s = 0.0;
    for (int i = tid; i < 145; i += 256) s += (double)ws[OFF_GPART + i];
    double dl = 0.0;
    for (int i = tid; i < GRID_D; i += 256) dl += (double)ws[OFF_DLP + i];
    s += dl / Nn;
    redd[tid] = s;
    __syncthreads();
    for (int off = 128; off; off >>= 1) {
        if (tid < off) redd[tid] += redd[tid + off];
        __syncthreads();
    }
    if (tid == 0) out[0] = (float)redd[0];
}

// ------- host-side constant math (runs ONCE at dlopen, never inside launch) -------

static void build_K_f(double ls_in, float Kf[52][52]) {
    float ls = (float)ls_in;
    float ls2 = ls * ls;
    for (int i = 0; i < 52; ++i)
        for (int j = 0; j < 52; ++j) {
            float sq = (float)((i - j) * (i - j));
            float arg = (-0.5f * sq) / ls2;
            Kf[i][j] = expf(arg);
        }
}

static void jacobi_eig(double a[52][52], double ev[52]) {
    const int n = 52;
    for (int sweep = 0; sweep < 100; ++sweep) {
        double off = 0;
        for (int p = 0; p < n - 1; ++p)
            for (int q = p + 1; q < n; ++q) off += a[p][q] * a[p][q];
        if (off < 1e-24) break;
        for (int p = 0; p < n - 1; ++p)
            for (int q = p + 1; q < n; ++q) {
                double apq = a[p][q];
                if (fabs(apq) < 1e-300) continue;
                double th = (a[q][q] - a[p][p]) / (2.0 * apq);
                double t = (th >= 0 ? 1.0 : -1.0) / (fabs(th) + sqrt(th * th + 1.0));
                double c = 1.0 / sqrt(t * t + 1.0), s = t * c;
                for (int i = 0; i < n; ++i) {
                    double aip = a[i][p], aiq = a[i][q];
                    a[i][p] = c * aip - s * aiq;
                    a[i][q] = s * aip + c * aiq;
                }
                for (int i = 0; i < n; ++i) {
                    double api = a[p][i], aqi = a[q][i];
                    a[p][i] = c * api - s * aqi;
                    a[q][i] = s * api + c * aqi;
                }
            }
    }
    for (int i = 0; i < n; ++i) ev[i] = a[i][i];
}

static void build_A(const float Kf[52][52], double jitter, double A[52][52]) {
    float jf = (float)jitter;
    for (int i = 0; i < 52; ++i)
        for (int j = 0; j < 52; ++j) A[i][j] = (double)Kf[i][j];
    for (int i = 0; i < 52; ++i) A[i][i] = (double)(float)(Kf[i][i] + jf);
}

static double cond_of(const float Kf[52][52], double jitter) {
    double A[52][52], ev[52];
    build_A(Kf, jitter, A);
    jacobi_eig(A, ev);
    double mx = 0.0, mn = 1e300;
    for (int i = 0; i < 52; ++i) {
        double a = fabs(ev[i]);
        if (a > mx) mx = a;
        if (a < mn) mn = a;
    }
    if (mn <= 0.0) return 1e300;
    return mx / mn;
}

static double find_jitter(const float Kf[52][52]) {
    double jitter = 1e-4;
    while (true) {
        if (cond_of(Kf, jitter) < 1e4) break;
        jitter *= 2.0;
        if (jitter > 0.1) break;
    }
    return jitter;
}

static void chol_inv_scaled(const float Kf[52][52], double jitter, double scale,
                            float* out) {
    const int n = 52;
    double A[52][52], L[52][52];
    build_A(Kf, jitter, A);
    memset(L, 0, sizeof(L));
    for (int j = 0; j < n; ++j) {
        double s = A[j][j];
        for (int k = 0; k < j; ++k) s -= L[j][k] * L[j][k];
        L[j][j] = sqrt(s);
        for (int i = j + 1; i < n; ++i) {
            double v = A[i][j];
            for (int k = 0; k < j; ++k) v -= L[i][k] * L[j][k];
            L[i][j] = v / L[j][j];
        }
    }
    for (int c = 0; c < n; ++c) {
        double y[52], x[52];
        for (int i = 0; i < n; ++i) {
            double v = (i == c) ? 1.0 : 0.0;
            for (int k = 0; k < i; ++k) v -= L[i][k] * y[k];
            y[i] = v / L[i][i];
        }
        for (int i = n - 1; i >= 0; --i) {
            double v = y[i];
            for (int k = i + 1; k < n; ++k) v -= L[k][i] * x[k];
            x[i] = v / L[i][i];
        }
        for (int i = 0; i < n; ++i) out[i * 52 + c] = (float)(x[i] * scale);
    }
}

struct KinvInit {
    float* w;   // PINNED: [0:2704) Kinv_lam*0.5/N, [2704:5408) Kinv_phi*0.5/D
    KinvInit() {
        if (hipHostMalloc((void**)&w, 5408 * sizeof(float)) != hipSuccess)
            w = (float*)malloc(5408 * sizeof(float));
        float Kf[52][52];
        build_K_f(52.0 / 4.0, Kf);
        chol_inv_scaled(Kf, find_jitter(Kf), 0.5 / Nn, w);
        build_K_f(52.0 / 3.0, Kf);
        chol_inv_scaled(Kf, find_jitter(Kf), 0.5 / Dd, w + 2704);
    }
};
static KinvInit g_kinv;   // dlopen-time; kernel_launch identical every call

// ---------------- launch: memcpy + 2 kernels ----------------

extern "C" void kernel_launch(void* const* d_in, const int* in_sizes, int n_in,
                              void* d_out, int out_size, void* d_ws, size_t ws_size,
                              hipStream_t stream) {
    (void)in_sizes; (void)n_in; (void)out_size; (void)ws_size;
    const float* lam        = (const float*)d_in[0];
    const float* phi        = (const float*)d_in[1];
    const float* gamma      = (const float*)d_in[2];
    const float* G          = (const float*)d_in[3];
    const float* Y          = (const float*)d_in[4];
    const float* logit_prev = (const float*)d_in[5];
    const int*   ev         = (const int*)d_in[6];
    float* out = (float*)d_out;
    float* ws  = (float*)d_ws;

    hipMemcpyAsync(ws + OFF_W, g_kinv.w, 5408 * sizeof(float),
                   hipMemcpyHostToDevice, stream);

    prep_kernel<<<RB_TOTAL, 256, 0, stream>>>(
        lam, phi, gamma, G, logit_prev, ev, Y,
        ws + OFF_THETA, ws + OFF_PHIP, (unsigned int*)(ws + OFF_EVP),
        ws + OFF_W, ws + OFF_GPART, (unsigned int*)(ws + OFF_CNT));
    data_kernel<<<GRID_D, 256, 0, stream>>>(
        ws + OFF_THETA, ws + OFF_PHIP, (const uint2*)(ws + OFF_EVP),
        ws, out, (unsigned int*)(ws + OFF_CNT));
}

// Round 12
// 433.816 us; speedup vs baseline: 1.3078x; 1.0027x over previous
//
#include <hip/hip_runtime.h>
#include <math.h>
#include <string.h>

#define Nn 4000
#define Dd 256
#define Tt 52
#define Kk 20
#define Pp 100
#define CH 4          // t-chunks for data kernel
#define TC 13         // Tt / CH
#define GRID_D ((Nn / 8) * CH)   // 2000

// ws layout (float offsets) — every slot read later is written every launch
#define OFF_W       0        // 5408: Kinv_lam*0.5/N | Kinv_phi*0.5/D (memcpy'd)
#define OFF_GPART   5408     // 145 per-gram-block scalars <W, M_block> (end 5553)
#define OFF_DLP     5556     // 2000 per-block data-loss partials (end 7556)
#define OFF_CNT     7556     // completion counter (pad to 7560)
#define OFF_EVP     7560     // uint2[ng][d]: bytes = e | (Y<<7); 256000 floats
#define OFF_PHIP    263560   // [t][k][d] : 266240 floats (end 529800)

#define GR_ROWS 128

// prep role ranges (theta role REMOVED — softmax fused into data kernel)
#define RB_PHIP0   0      // 52 blocks: sigmoid(phi) transpose
#define RB_GPHI0   52     // 20 blocks: gram(phi dev) . W_phi -> gpart[125+slot]
#define RB_GLAM0   72     // 125 blocks: gram(lam dev) . W_lam -> gpart[slot]
#define RB_EVY0    197    // 1000 blocks: ev + Y-at-event -> packed bytes
#define RB_TOTAL   1197

// ---------------- merged prep kernel ----------------
__global__ __launch_bounds__(256) void prep_kernel(
    const float* __restrict__ lam, const float* __restrict__ phi,
    const float* __restrict__ gamma, const float* __restrict__ G,
    const float* __restrict__ logit_prev, const int* __restrict__ ev,
    const float* __restrict__ Y,
    float* __restrict__ phip_t, unsigned int* __restrict__ evy,
    const float* __restrict__ W, float* __restrict__ gpart,
    unsigned int* __restrict__ cnt) {
    __shared__ float rows[GR_ROWS][56];
    __shared__ float meanv[GR_ROWS];
    __shared__ double redd[256];
    const int bx = blockIdx.x, tid = threadIdx.x;

    if (bx < RB_GPHI0) {
        if (bx == 0 && tid == 0) *cnt = 0u;          // completion counter reset
        // phip_t[t][k][d] = sigmoid(phi[k][d][t]); thread per (d,t)
        int gid = bx * 256 + tid;                    // d*52 + t
        int d = gid / Tt, t = gid - d * Tt;
        float v[Kk];
#pragma unroll
        for (int k = 0; k < Kk; ++k) {
            float x = phi[k * (Dd * Tt) + gid];      // coalesced in t
            v[k] = 1.f / (1.f + __expf(-x));
        }
#pragma unroll
        for (int k = 0; k < Kk; ++k)
            phip_t[((size_t)t * Kk + k) * Dd + d] = v[k];
        return;
    }
    if (bx < RB_GLAM0) {
        // <W_phi, Gram of (phi - logit_prev) over 2 tiles> -> gpart[125+slot]
        int slot = bx - RB_GPHI0;                    // 0..19
        int ta = tid % 13, tb = tid / 13;
        float acc[4][4] = {};
        for (int it = 0; it < 2; ++it) {
            int R0 = (slot * 2 + it) * GR_ROWS;
            __syncthreads();
            for (int idx = tid; idx < GR_ROWS * Tt; idx += 256) {
                int r = idx / Tt, t = idx - r * Tt;
                int R = R0 + r;
                rows[r][t] = phi[R * Tt + t] - logit_prev[(R & 255) * Tt + t];
            }
            __syncthreads();
            if (tb < 13) {
                for (int r = 0; r < GR_ROWS; ++r) {
                    float4 a = *(const float4*)&rows[r][4 * ta];
                    float4 b = *(const float4*)&rows[r][4 * tb];
                    float av[4] = {a.x, a.y, a.z, a.w};
                    float bv[4] = {b.x, b.y, b.z, b.w};
#pragma unroll
                    for (int i = 0; i < 4; ++i)
#pragma unroll
                        for (int j = 0; j < 4; ++j) acc[i][j] += av[i] * bv[j];
                }
            }
        }
        double s = 0.0;
        if (tb < 13)
#pragma unroll
            for (int i = 0; i < 4; ++i)
#pragma unroll
                for (int j = 0; j < 4; ++j)
                    s += (double)acc[i][j] *
                         (double)W[2704 + (4 * ta + i) * Tt + 4 * tb + j];
        redd[tid] = s;
        __syncthreads();
        for (int off = 128; off; off >>= 1) {
            if (tid < off) redd[tid] += redd[tid + off];
            __syncthreads();
        }
        if (tid == 0) gpart[125 + slot] = (float)redd[0];
        return;
    }
    if (bx < RB_EVY0) {
        // <W_lam, Gram of (lambda - G@gamma) over 5 tiles> -> gpart[slot]
        int slot = bx - RB_GLAM0;                    // 0..124
        int ta = tid % 13, tb = tid / 13;
        float acc[4][4] = {};
        for (int it = 0; it < 5; ++it) {
            int R0 = (slot * 5 + it) * GR_ROWS;
            __syncthreads();
            if (tid < GR_ROWS) {
                int R = R0 + tid;
                int n = R / Kk, k = R - n * Kk;
                float m = 0.f;
                for (int p = 0; p < Pp; ++p) m += G[n * Pp + p] * gamma[p * Kk + k];
                meanv[tid] = m;
            }
            __syncthreads();
            for (int idx = tid; idx < GR_ROWS * Tt; idx += 256) {
                int r = idx / Tt, t = idx - r * Tt;
                int R = R0 + r;
                rows[r][t] = lam[R * Tt + t] - meanv[r];
            }
            __syncthreads();
            if (tb < 13) {
                for (int r = 0; r < GR_ROWS; ++r) {
                    float4 a = *(const float4*)&rows[r][4 * ta];
                    float4 b = *(const float4*)&rows[r][4 * tb];
                    float av[4] = {a.x, a.y, a.z, a.w};
                    float bv[4] = {b.x, b.y, b.z, b.w};
#pragma unroll
                    for (int i = 0; i < 4; ++i)
#pragma unroll
                        for (int j = 0; j < 4; ++j) acc[i][j] += av[i] * bv[j];
                }
            }
        }
        double s = 0.0;
        if (tb < 13)
#pragma unroll
            for (int i = 0; i < 4; ++i)
#pragma unroll
                for (int j = 0; j < 4; ++j)
                    s += (double)acc[i][j] *
                         (double)W[(4 * ta + i) * Tt + 4 * tb + j];
        redd[tid] = s;
        __syncthreads();
        for (int off = 128; off; off >>= 1) {
            if (tid < off) redd[tid] += redd[tid + off];
            __syncthreads();
        }
        if (tid == 0) gpart[slot] = (float)redd[0];
        return;
    }
    {
        // evy: block per (ng, half); thread d packs 4 n's: byte = e | (Y@e)<<7.
        // Owns the 65-MB random-line Y gather (1000 dedicated blocks).
        int idx = bx - RB_EVY0;                      // 0..999
        int ng = idx >> 1, half = idx & 1;
        int n0 = ng * 8 + half * 4;
        unsigned a = 0;
#pragma unroll
        for (int g = 0; g < 4; ++g) {
            int nd = (n0 + g) * Dd + tid;
            unsigned e = (unsigned)ev[nd] & 63u;     // coalesced
            float y = __builtin_nontemporal_load(Y + (size_t)nd * Tt + e);
            a |= (e | (y > 0.5f ? 128u : 0u)) << (8 * g);
        }
        evy[((size_t)ng * Dd + tid) * 2 + half] = a;
        return;
    }
}

// ---------------- data loss kernel: fused softmax + folded final ----------------
// grid 2000: ng = blockIdx>>2 (8 n's), chunk = blockIdx&3 (13 t's), 256 d-lanes.
// lambda staged once per block (chunks partition t -> lam read once grid-wide),
// softmax in-block, thS read via conflict-free same-address ds_read_b128.
__global__ __launch_bounds__(256) void data_kernel(const float* __restrict__ lam,
                                                   const float* __restrict__ phip_t,
                                                   const uint2* __restrict__ evy,
                                                   float* __restrict__ ws,
                                                   float* __restrict__ out,
                                                   unsigned int* __restrict__ cnt) {
    __shared__ __align__(16) float thS[TC][8][Kk];   // 8.32 KB
    __shared__ float lamS[8][Kk][TC + 1];            // 4.48 KB
    __shared__ float wsum[4];
    __shared__ double redd[256];
    __shared__ int isLast;
    const int tid = threadIdx.x;
    const int d = tid;
    const int ng = blockIdx.x >> 2;
    const int t0 = (blockIdx.x & 3) * TC;
    const int n0 = ng * 8;

    // Phase A: stage lambda slice [8 n][20 k][13 t]
    if (tid < 8 * Kk) {
        int n = tid / Kk, k = tid - n * Kk;
        const float* src = lam + ((size_t)(n0 + n) * Kk + k) * Tt + t0;
#pragma unroll
        for (int j = 0; j < TC; ++j) lamS[n][k][j] = src[j];
    }
    __syncthreads();
    // Phase B: softmax over k per (n, j)
    if (tid < 8 * TC) {
        int n = tid / TC, j = tid - n * TC;
        float v[Kk];
        float m = -1e30f;
#pragma unroll
        for (int k = 0; k < Kk; ++k) { v[k] = lamS[n][k][j]; m = fmaxf(m, v[k]); }
        float s = 0.f;
#pragma unroll
        for (int k = 0; k < Kk; ++k) { v[k] = __expf(v[k] - m); s += v[k]; }
        float inv = 1.f / s;
#pragma unroll
        for (int k = 0; k < Kk; ++k) thS[j][n][k] = v[k] * inv;
    }

    // per-(n,d) event data from packed bytes (overlaps phases A/B)
    uint2 ee = evy[(size_t)ng * Dd + d];             // ONE coalesced 8B load
    int e[8];
    float Yv[8], acc[8], pie[8], prod[8];
#pragma unroll
    for (int g = 0; g < 8; ++g) {
        unsigned byte = ((g < 4 ? ee.x : ee.y) >> (8 * (g & 3))) & 255u;
        e[g] = (int)(byte & 63u);
        Yv[g] = (byte & 128u) ? 1.f : 0.f;
        acc[g] = 0.f; prod[g] = 1.f; pie[g] = 0.5f;  // non-owning chunks -> term 0
    }
    __syncthreads();

    for (int j = 0; j < TC; ++j) {
        int t = t0 + j;
        float pv[Kk];
        const float* pt = phip_t + (size_t)t * (Kk * Dd) + d;
#pragma unroll
        for (int k = 0; k < Kk; ++k) pv[k] = pt[k * Dd];   // coalesced, L2-hot
#pragma unroll
        for (int g = 0; g < 8; ++g) {
            const float4* th = (const float4*)&thS[j][g][0];  // LDS broadcast
            float4 a0 = th[0], a1 = th[1], a2 = th[2], a3 = th[3], a4 = th[4];
            float pi = a0.x * pv[0] + a0.y * pv[1] + a0.z * pv[2] + a0.w * pv[3]
                     + a1.x * pv[4] + a1.y * pv[5] + a1.z * pv[6] + a1.w * pv[7]
                     + a2.x * pv[8] + a2.y * pv[9] + a2.z * pv[10] + a2.w * pv[11]
                     + a3.x * pv[12] + a3.y * pv[13] + a3.z * pv[14] + a3.w * pv[15]
                     + a4.x * pv[16] + a4.y * pv[17] + a4.z * pv[18] + a4.w * pv[19];
            pi = fminf(fmaxf(pi, 1e-8f), 1.0f - 1e-8f);
            prod[g] *= (t <= e[g]) ? (1.f - pi) : 1.f;     // >= 1e-32 per 4-group
            pie[g] = (t == e[g]) ? pi : pie[g];
        }
        if ((j & 3) == 3 || j == TC - 1) {
#pragma unroll
            for (int g = 0; g < 8; ++g) { acc[g] += __logf(prod[g]); prod[g] = 1.f; }
        }
    }
    float tsum = 0.f;
#pragma unroll
    for (int g = 0; g < 8; ++g)
        tsum += acc[g] + Yv[g] * (__logf(pie[g]) - __logf(1.f - pie[g]));
    for (int off = 32; off; off >>= 1) tsum += __shfl_down(tsum, off, 64);
    if ((tid & 63) == 0) wsum[tid >> 6] = tsum;
    __syncthreads();
    if (tid == 0) {
        ws[OFF_DLP + blockIdx.x] = -(wsum[0] + wsum[1] + wsum[2] + wsum[3]);
        __threadfence();                             // release DLp
        unsigned prev = atomicAdd(cnt, 1u);
        isLast = (prev == GRID_D - 1) ? 1 : 0;
    }
    __syncthreads();
    if (!isLast) return;

    // ---- folded final: 145 gram scalars + 2000 DLp (8.6 KB total) ----
    __threadfence();                                 // acquire others' DLp
    double s = 0.0;
    for (int i = tid; i < 145; i += 256) s += (double)ws[OFF_GPART + i];
    double dl = 0.0;
    for (int i = tid; i < GRID_D; i += 256) dl += (double)ws[OFF_DLP + i];
    s += dl / Nn;
    redd[tid] = s;
    __syncthreads();
    for (int off = 128; off; off >>= 1) {
        if (tid < off) redd[tid] += redd[tid + off];
        __syncthreads();
    }
    if (tid == 0) out[0] = (float)redd[0];
}

// ------- host-side constant math (runs ONCE at dlopen, never inside launch) -------

static void build_K_f(double ls_in, float Kf[52][52]) {
    float ls = (float)ls_in;
    float ls2 = ls * ls;
    for (int i = 0; i < 52; ++i)
        for (int j = 0; j < 52; ++j) {
            float sq = (float)((i - j) * (i - j));
            float arg = (-0.5f * sq) / ls2;
            Kf[i][j] = expf(arg);
        }
}

static void jacobi_eig(double a[52][52], double ev[52]) {
    const int n = 52;
    for (int sweep = 0; sweep < 100; ++sweep) {
        double off = 0;
        for (int p = 0; p < n - 1; ++p)
            for (int q = p + 1; q < n; ++q) off += a[p][q] * a[p][q];
        if (off < 1e-24) break;
        for (int p = 0; p < n - 1; ++p)
            for (int q = p + 1; q < n; ++q) {
                double apq = a[p][q];
                if (fabs(apq) < 1e-300) continue;
                double th = (a[q][q] - a[p][p]) / (2.0 * apq);
                double t = (th >= 0 ? 1.0 : -1.0) / (fabs(th) + sqrt(th * th + 1.0));
                double c = 1.0 / sqrt(t * t + 1.0), s = t * c;
                for (int i = 0; i < n; ++i) {
                    double aip = a[i][p], aiq = a[i][q];
                    a[i][p] = c * aip - s * aiq;
                    a[i][q] = s * aip + c * aiq;
                }
                for (int i = 0; i < n; ++i) {
                    double api = a[p][i], aqi = a[q][i];
                    a[p][i] = c * api - s * aqi;
                    a[q][i] = s * api + c * aqi;
                }
            }
    }
    for (int i = 0; i < n; ++i) ev[i] = a[i][i];
}

static void build_A(const float Kf[52][52], double jitter, double A[52][52]) {
    float jf = (float)jitter;
    for (int i = 0; i < 52; ++i)
        for (int j = 0; j < 52; ++j) A[i][j] = (double)Kf[i][j];
    for (int i = 0; i < 52; ++i) A[i][i] = (double)(float)(Kf[i][i] + jf);
}

static double cond_of(const float Kf[52][52], double jitter) {
    double A[52][52], ev[52];
    build_A(Kf, jitter, A);
    jacobi_eig(A, ev);
    double mx = 0.0, mn = 1e300;
    for (int i = 0; i < 52; ++i) {
        double a = fabs(ev[i]);
        if (a > mx) mx = a;
        if (a < mn) mn = a;
    }
    if (mn <= 0.0) return 1e300;
    return mx / mn;
}

static double find_jitter(const float Kf[52][52]) {
    double jitter = 1e-4;
    while (true) {
        if (cond_of(Kf, jitter) < 1e4) break;
        jitter *= 2.0;
        if (jitter > 0.1) break;
    }
    return jitter;
}

static void chol_inv_scaled(const float Kf[52][52], double jitter, double scale,
                            float* out) {
    const int n = 52;
    double A[52][52], L[52][52];
    build_A(Kf, jitter, A);
    memset(L, 0, sizeof(L));
    for (int j = 0; j < n; ++j) {
        double s = A[j][j];
        for (int k = 0; k < j; ++k) s -= L[j][k] * L[j][k];
        L[j][j] = sqrt(s);
        for (int i = j + 1; i < n; ++i) {
            double v = A[i][j];
            for (int k = 0; k < j; ++k) v -= L[i][k] * L[j][k];
            L[i][j] = v / L[j][j];
        }
    }
    for (int c = 0; c < n; ++c) {
        double y[52], x[52];
        for (int i = 0; i < n; ++i) {
            double v = (i == c) ? 1.0 : 0.0;
            for (int k = 0; k < i; ++k) v -= L[i][k] * y[k];
            y[i] = v / L[i][i];
        }
        for (int i = n - 1; i >= 0; --i) {
            double v = y[i];
            for (int k = i + 1; k < n; ++k) v -= L[k][i] * x[k];
            x[i] = v / L[i][i];
        }
        for (int i = 0; i < n; ++i) out[i * 52 + c] = (float)(x[i] * scale);
    }
}

struct KinvInit {
    float* w;   // PINNED: [0:2704) Kinv_lam*0.5/N, [2704:5408) Kinv_phi*0.5/D
    KinvInit() {
        if (hipHostMalloc((void**)&w, 5408 * sizeof(float)) != hipSuccess)
            w = (float*)malloc(5408 * sizeof(float));
        float Kf[52][52];
        build_K_f(52.0 / 4.0, Kf);
        chol_inv_scaled(Kf, find_jitter(Kf), 0.5 / Nn, w);
        build_K_f(52.0 / 3.0, Kf);
        chol_inv_scaled(Kf, find_jitter(Kf), 0.5 / Dd, w + 2704);
    }
};
static KinvInit g_kinv;   // dlopen-time; kernel_launch identical every call

// ---------------- launch: memcpy + 2 kernels ----------------

extern "C" void kernel_launch(void* const* d_in, const int* in_sizes, int n_in,
                              void* d_out, int out_size, void* d_ws, size_t ws_size,
                              hipStream_t stream) {
    (void)in_sizes; (void)n_in; (void)out_size; (void)ws_size;
    const float* lam        = (const float*)d_in[0];
    const float* phi        = (const float*)d_in[1];
    const float* gamma      = (const float*)d_in[2];
    const float* G          = (const float*)d_in[3];
    const float* Y          = (const float*)d_in[4];
    const float* logit_prev = (const float*)d_in[5];
    const int*   ev         = (const int*)d_in[6];
    float* out = (float*)d_out;
    float* ws  = (float*)d_ws;

    hipMemcpyAsync(ws + OFF_W, g_kinv.w, 5408 * sizeof(float),
                   hipMemcpyHostToDevice, stream);

    prep_kernel<<<RB_TOTAL, 256, 0, stream>>>(
        lam, phi, gamma, G, logit_prev, ev, Y,
        ws + OFF_PHIP, (unsigned int*)(ws + OFF_EVP),
        ws + OFF_W, ws + OFF_GPART, (unsigned int*)(ws + OFF_CNT));
    data_kernel<<<GRID_D, 256, 0, stream>>>(
        lam, ws + OFF_PHIP, (const uint2*)(ws + OFF_EVP),
        ws, out, (unsigned int*)(ws + OFF_CNT));
}